// Round 10
// baseline (62.077 us; speedup 1.0000x reference)
//
#include <hip/hip_runtime.h>
#include <hip/hip_bf16.h>

typedef __attribute__((ext_vector_type(8))) short s16x8;
typedef __attribute__((ext_vector_type(4))) float f32x4;

#define NEGC 1000000000000.0f

constexpr int B_ = 8, S_ = 512, H_ = 768;
constexpr int ENT = 12, ARG = 16;
constexpr int NC = 320;
constexpr int ROWS = B_ * S_;        // 4096
constexpr size_t OUT_ENT = (size_t)B_ * ENT * S_ * S_;

static __device__ __forceinline__ unsigned short f2bf(float x) {
  return __builtin_bit_cast(unsigned short, __float2bfloat16(x));
}

typedef const __attribute__((address_space(1))) unsigned int gu32;
typedef __attribute__((address_space(3))) unsigned int lu32;
static __device__ __forceinline__ void glds16(const void* g, void* l) {
  __builtin_amdgcn_global_load_lds((gu32*)g, (lu32*)l, 16, 0, 0);
}

// ---------------------------------------------------------------------------
// Kernel 1: round-5 prep (exact).
// ---------------------------------------------------------------------------
__global__ __launch_bounds__(256) void k_prep(
    const float* __restrict__ X,
    const float* __restrict__ W1, const float* __restrict__ b1,
    const float* __restrict__ W2, const float* __restrict__ b2,
    const float* __restrict__ Wa1, const float* __restrict__ ba1,
    const float* __restrict__ Wa2, const float* __restrict__ ba2,
    __hip_bfloat16* __restrict__ Xb,
    __hip_bfloat16* __restrict__ Wt,
    float* __restrict__ bcat) {
  int idx = blockIdx.x * 256 + threadIdx.x;
  const int nx = ROWS * H_ / 4;
  if (idx < nx) {
    float4 v = reinterpret_cast<const float4*>(X)[idx];
    ushort4 o;
    o.x = f2bf(v.x); o.y = f2bf(v.y); o.z = f2bf(v.z); o.w = f2bf(v.w);
    reinterpret_cast<ushort4*>(Xb)[idx] = o;
    return;
  }
  idx -= nx;
  if (idx < NC * H_) {
    int n = idx / H_;
    int k = idx - n * H_;
    float v = 0.0f;
    if (n < 128)      v = W1[k * 128 + n];
    else if (n < 152) v = W2[k * 24 + (n - 128)];
    else if (n < 280) v = Wa1[k * 128 + (n - 152)];
    else if (n < 312) v = Wa2[k * 32 + (n - 280)];
    reinterpret_cast<unsigned short*>(Wt)[(size_t)n * H_ + k] = f2bf(v);
    return;
  }
  idx -= NC * H_;
  if (idx < NC) {
    int n = idx;
    float v = 0.0f;
    if (n < 128)      v = b1[n];
    else if (n < 152) v = b2[n - 128];
    else if (n < 280) v = ba1[n - 152];
    else if (n < 312) v = ba2[n - 280];
    bcat[n] = v;
  }
}

// ---------------------------------------------------------------------------
// Kernel 2: LDS-staged fused GEMM (exact round-9; measured 22.5 -> ~6-7us).
// ---------------------------------------------------------------------------
__global__ __launch_bounds__(256) void k_gemm(
    const __hip_bfloat16* __restrict__ Xb,
    const __hip_bfloat16* __restrict__ Wt,
    const float* __restrict__ bcat,
    __hip_bfloat16* __restrict__ qwe, __hip_bfloat16* __restrict__ kwe,
    __hip_bfloat16* __restrict__ qwa, __hip_bfloat16* __restrict__ kwa,
    float* __restrict__ kbe, float* __restrict__ qbe,
    float* __restrict__ kba, float* __restrict__ qba) {
  __shared__ __hip_bfloat16 XA[2][32 * 64];   // 8 KB
  __shared__ __hip_bfloat16 WA[2][64 * 64];   // 16 KB
  const int tid  = threadIdx.x;
  const int lane = tid & 63;
  const int w    = tid >> 6;
  const int wm   = w & 1;
  const int wn   = w >> 1;
  const int rl   = lane & 15;
  const int rg   = lane >> 4;
  const int row0 = blockIdx.y * 32;
  const int col0 = blockIdx.x * 64;
  const int lr = lane >> 3, cc = lane & 7;
  const int scs = cc ^ lr;

  const short* Xs = reinterpret_cast<const short*>(Xb);
  const short* Ws = reinterpret_cast<const short*>(Wt);
  const size_t xsrc  = (size_t)(row0 + w * 8 + lr) * H_ + scs * 8;
  const size_t wsrc0 = (size_t)(col0 + w * 16 + lr) * H_ + scs * 8;
  const size_t wsrc1 = (size_t)(col0 + w * 16 + 8 + lr) * H_ + scs * 8;

  auto stage = [&](int t, int buf) {
    const size_t ko = (size_t)t * 64;
    glds16(Xs + xsrc + ko,  &XA[buf][(w * 8) * 64]);
    glds16(Ws + wsrc0 + ko, &WA[buf][(w * 16) * 64]);
    glds16(Ws + wsrc1 + ko, &WA[buf][(w * 16 + 8) * 64]);
  };

  f32x4 acc[2] = {};
  auto compute = [&](int buf) {
    const short* xl = reinterpret_cast<const short*>(XA[buf]);
    const short* wl = reinterpret_cast<const short*>(WA[buf]);
#pragma unroll
    for (int ks = 0; ks < 2; ++ks) {
      const int gc = ks * 4 + rg;
      const int mloc = wm * 16 + rl;
      s16x8 bfrag = *reinterpret_cast<const s16x8*>(xl + mloc * 64 + (gc ^ (rl & 7)) * 8);
#pragma unroll
      for (int ni = 0; ni < 2; ++ni) {
        const int nloc = wn * 32 + ni * 16 + rl;
        s16x8 afrag = *reinterpret_cast<const s16x8*>(wl + nloc * 64 + (gc ^ (rl & 7)) * 8);
        acc[ni] = __builtin_amdgcn_mfma_f32_16x16x32_bf16(afrag, bfrag, acc[ni], 0, 0, 0);
      }
    }
  };

  stage(0, 0);
  asm volatile("s_waitcnt vmcnt(0)" ::: "memory");
  __syncthreads();
#pragma unroll 2
  for (int t = 0; t < 12; ++t) {
    if (t < 11) stage(t + 1, (t + 1) & 1);
    compute(t & 1);
    asm volatile("s_waitcnt vmcnt(0)" ::: "memory");
    __syncthreads();
  }

  const int r = row0 + wm * 16 + rl;
  const int b = r >> 9, mm = r & 511;
#pragma unroll
  for (int ni = 0; ni < 2; ++ni) {
    const int nq = col0 + wn * 32 + ni * 16 + rg * 4;
    if (nq >= 312) continue;
    float4 bc = *reinterpret_cast<const float4*>(bcat + nq);
    float v0 = acc[ni][0] + bc.x;
    float v1 = acc[ni][1] + bc.y;
    float v2 = acc[ni][2] + bc.z;
    float v3 = acc[ni][3] + bc.w;
    if (nq < 128 || (nq >= 152 && nq < 280)) {
      const bool ent = nq < 128;
      const int p = (ent ? nq : nq - 152) >> 2;
      float inv = exp2f(-(float)p * 0.4152410118609203f);
      float s, c;
      sincosf((float)mm * inv, &s, &c);
      unsigned int qpk = (unsigned int)f2bf(v0 * c - v2 * s) |
                         ((unsigned int)f2bf(v2 * c + v0 * s) << 16);
      unsigned int kpk = (unsigned int)f2bf(v1 * c - v3 * s) |
                         ((unsigned int)f2bf(v3 * c + v1 * s) << 16);
      short* qd = reinterpret_cast<short*>(ent ? qwe : qwa);
      short* kd = reinterpret_cast<short*>(ent ? kwe : kwa);
      *reinterpret_cast<unsigned int*>(qd + (size_t)r * 64 + 2 * p) = qpk;
      *reinterpret_cast<unsigned int*>(kd + (size_t)r * 64 + 2 * p) = kpk;
    } else {
      const bool ent = nq < 152;
      const int base = ent ? 128 : 280;
      const int T = ent ? ENT : ARG;
      float* qb = ent ? qbe : qba;
      float* kb = ent ? kbe : kba;
      float vv[4] = {v0, v1, v2, v3};
#pragma unroll
      for (int q = 0; q < 4; ++q) {
        int e = nq - base + q;
        int t = e >> 1;
        float* dst = (e & 1) ? qb : kb;
        dst[((size_t)b * T + t) * S_ + mm] = vv[q] * 0.5f;
      }
    }
  }
}

// ---------------------------------------------------------------------------
// Kernel 3: round-5 bcast + bias-planes staged in LDS (T14 style: issue
// global loads -> qk MFMA hides latency -> ds_write -> sync). The 28-plane
// t-loop then reads qv/kv from LDS instead of 8 dependent global loads per
// plane. Store pattern/orientation unchanged (single-variable change).
// ---------------------------------------------------------------------------
__global__ __launch_bounds__(256) void k_bcast(
    const __hip_bfloat16* __restrict__ qwe, const __hip_bfloat16* __restrict__ kwe,
    const __hip_bfloat16* __restrict__ qwa, const __hip_bfloat16* __restrict__ kwa,
    const float* __restrict__ kbe, const float* __restrict__ qbe,
    const float* __restrict__ kba, const float* __restrict__ qba,
    const int* __restrict__ mask,
    float* __restrict__ out) {
  __shared__ float qbl[28][64];  // [plane][block m-row]   (7 KB)
  __shared__ float kbl[28][64];  // [plane][block n-col]   (7 KB)
  const int tid  = threadIdx.x;
  const int lane = tid & 63;
  const int w    = tid >> 6;
  const int b    = blockIdx.z;
  const int M0   = blockIdx.y * 64;
  const int N0   = blockIdx.x * 64;
  const int m0   = M0 + w * 16;
  const int n0   = N0;
  const int col  = lane & 15;
  const int rg   = lane >> 4;
  const int kseg = rg * 8;

  // ---- Stage bias planes: issue 14 loads/thread (7 q-side + 7 k-side) ----
  float stg[14];
#pragma unroll
  for (int i = 0; i < 14; ++i) {
    const int side = i / 7;           // 0 = q-bias (rows), 1 = k-bias (cols)
    const int pl   = (i % 7) * 4 + w; // plane 0..27
    const bool e   = pl < 12;
    const float* src = side == 0 ? (e ? qbe : qba) : (e ? kbe : kba);
    const size_t pbase = e ? ((size_t)b * ENT + pl) * S_
                           : ((size_t)b * ARG + (pl - 12)) * S_;
    stg[i] = src[pbase + (side == 0 ? M0 : N0) + lane];
  }

  int mrow[4];
  float mqv[4], sqv[4];
#pragma unroll
  for (int j = 0; j < 4; ++j) {
    mrow[j] = m0 + rg * 4 + j;
    float mf = (float)mask[b * S_ + mrow[j]];
    mqv[j] = mf; sqv[j] = NEGC * (1.0f - mf);
  }
  int ncol[4];
  float mkv[4], skv[4];
#pragma unroll
  for (int f = 0; f < 4; ++f) {
    ncol[f] = n0 + 16 * f + col;
    float mf = (float)mask[b * S_ + ncol[f]];
    mkv[f] = mf; skv[f] = NEGC * (1.0f - mf);
  }
  float M[4][4], O[4][4];
#pragma unroll
  for (int f = 0; f < 4; ++f)
#pragma unroll
    for (int j = 0; j < 4; ++j) {
      M[f][j] = mqv[j] * mkv[f];
      O[f][j] = sqv[j] * mkv[f] + skv[f] + ((ncol[f] < mrow[j]) ? NEGC : 0.0f);
    }

  // ---- qk MFMA for both heads (hides the staging-load latency) ----
  f32x4 acc_e[4] = {}, acc_a[4] = {};
  {
    const short* qs = reinterpret_cast<const short*>(qwe);
    const short* ks = reinterpret_cast<const short*>(kwe);
#pragma unroll
    for (int kk = 0; kk < 64; kk += 32) {
      s16x8 a = *reinterpret_cast<const s16x8*>(
          qs + (size_t)(b * S_ + m0 + col) * 64 + kk + kseg);
#pragma unroll
      for (int f = 0; f < 4; ++f) {
        s16x8 bb = *reinterpret_cast<const s16x8*>(
            ks + (size_t)(b * S_ + n0 + 16 * f + col) * 64 + kk + kseg);
        acc_e[f] = __builtin_amdgcn_mfma_f32_16x16x32_bf16(a, bb, acc_e[f], 0, 0, 0);
      }
    }
  }
  {
    const short* qs = reinterpret_cast<const short*>(qwa);
    const short* ks = reinterpret_cast<const short*>(kwa);
#pragma unroll
    for (int kk = 0; kk < 64; kk += 32) {
      s16x8 a = *reinterpret_cast<const s16x8*>(
          qs + (size_t)(b * S_ + m0 + col) * 64 + kk + kseg);
#pragma unroll
      for (int f = 0; f < 4; ++f) {
        s16x8 bb = *reinterpret_cast<const s16x8*>(
            ks + (size_t)(b * S_ + n0 + 16 * f + col) * 64 + kk + kseg);
        acc_a[f] = __builtin_amdgcn_mfma_f32_16x16x32_bf16(a, bb, acc_a[f], 0, 0, 0);
      }
    }
  }

  // ---- Write staged biases to LDS, sync ----
#pragma unroll
  for (int i = 0; i < 14; ++i) {
    const int side = i / 7;
    const int pl   = (i % 7) * 4 + w;
    if (side == 0) qbl[pl][lane] = stg[i];
    else           kbl[pl][lane] = stg[i];
  }
  __syncthreads();

  // ---- Stream planes: biases from LDS, stores unchanged ----
  auto head = [&](const f32x4* acc, int po, int T, size_t obase0) {
    float accMO[4][4];
#pragma unroll
    for (int f = 0; f < 4; ++f)
#pragma unroll
      for (int j = 0; j < 4; ++j)
        accMO[f][j] = acc[f][j] * 0.125f * M[f][j] - O[f][j];

    for (int t = 0; t < T; ++t) {
      float qv[4];
#pragma unroll
      for (int j = 0; j < 4; ++j) qv[j] = qbl[po + t][w * 16 + rg * 4 + j];
      float kv[4];
#pragma unroll
      for (int f = 0; f < 4; ++f) kv[f] = kbl[po + t][16 * f + col];
      size_t obase = obase0 + (size_t)t * S_ * S_;
#pragma unroll
      for (int f = 0; f < 4; ++f) {
#pragma unroll
        for (int j = 0; j < 4; ++j) {
          float v = fmaf(kv[f] + qv[j], M[f][j], accMO[f][j]);
          out[obase + (size_t)mrow[j] * S_ + ncol[f]] = v;
        }
      }
    }
  };

  head(acc_e, 0,  ENT, (size_t)b * ENT * S_ * S_);
  head(acc_a, 12, ARG, OUT_ENT + (size_t)b * ARG * S_ * S_);
}

// ---------------------------------------------------------------------------
extern "C" void kernel_launch(void* const* d_in, const int* in_sizes, int n_in,
                              void* d_out, int out_size, void* d_ws, size_t ws_size,
                              hipStream_t stream) {
  (void)in_sizes; (void)n_in; (void)out_size; (void)ws_size;
  const float* X   = (const float*)d_in[0];
  const int* mask  = (const int*)d_in[1];
  const float* W1  = (const float*)d_in[2];
  const float* b1  = (const float*)d_in[3];
  const float* W2  = (const float*)d_in[4];
  const float* b2  = (const float*)d_in[5];
  const float* Wa1 = (const float*)d_in[6];
  const float* ba1 = (const float*)d_in[7];
  const float* Wa2 = (const float*)d_in[8];
  const float* ba2 = (const float*)d_in[9];
  float* out = (float*)d_out;

  char* ws = (char*)d_ws;
  size_t off = 0;
  auto walloc = [&](size_t bytes) -> void* {
    void* p = ws + off;
    off += (bytes + 255) & ~(size_t)255;
    return p;
  };
  __hip_bfloat16* Xb  = (__hip_bfloat16*)walloc((size_t)ROWS * H_ * 2);
  __hip_bfloat16* Wt  = (__hip_bfloat16*)walloc((size_t)NC * H_ * 2);
  float* bcat         = (float*)walloc((size_t)NC * 4);
  __hip_bfloat16* qwe = (__hip_bfloat16*)walloc((size_t)ROWS * 64 * 2);
  __hip_bfloat16* kwe = (__hip_bfloat16*)walloc((size_t)ROWS * 64 * 2);
  __hip_bfloat16* qwa = (__hip_bfloat16*)walloc((size_t)ROWS * 64 * 2);
  __hip_bfloat16* kwa = (__hip_bfloat16*)walloc((size_t)ROWS * 64 * 2);
  float* kbe = (float*)walloc((size_t)B_ * ENT * S_ * 4);
  float* qbe = (float*)walloc((size_t)B_ * ENT * S_ * 4);
  float* kba = (float*)walloc((size_t)B_ * ARG * S_ * 4);
  float* qba = (float*)walloc((size_t)B_ * ARG * S_ * 4);

  const int prep_tasks = ROWS * H_ / 4 + NC * H_ + NC;
  k_prep<<<dim3((prep_tasks + 255) / 256), dim3(256), 0, stream>>>(
      X, W1, b1, W2, b2, Wa1, ba1, Wa2, ba2, Xb, Wt, bcat);
  k_gemm<<<dim3(5, 128), dim3(256), 0, stream>>>(
      Xb, Wt, bcat, qwe, kwe, qwa, kwa, kbe, qbe, kba, qba);
  k_bcast<<<dim3(8, 8, 8), dim3(256), 0, stream>>>(
      qwe, kwe, qwa, kwa, kbe, qbe, kba, qba, mask, out);
}